// Round 1
// baseline (2138.625 us; speedup 1.0000x reference)
//
#include <hip/hip_runtime.h>
#include <math.h>

// Geometry (no padding at these shapes):
//  C=96, NHEAD=8, dh=12, D,H,W = 24,96,96 ; wavelet grid 12,48,48
//  windows 4x8x8=256, Lq=6*12*12=864, Lk=3*6*6=108, chunks of 48 q-rows (18/window)

#define NKV 27648              // 12*48*48
// workspace offsets (floats)
#define OFF_TAB 0              // 324*96 = 31104 pos-table floats
#define OFF_GSUM 31104
#define OFF_GLO 31200
#define OFF_XM 31296
#define OFF_LOW (OFF_XM + NKV*96)
#define OFF_FRE (OFF_LOW + NKV*96)
#define OFF_KP  (OFF_FRE + NKV*96)
#define OFF_VP  (OFF_KP  + NKV*96)
// table sub-offsets (within tab): AzQ 0, AyQ 2304, AxQ 11520, AzK 20736, AyK 21888, AxK 26496

// ---------------- pos tables: tab[p*96+c], p in [0,324) ----------------
__global__ void k_pos(const float* __restrict__ pos_w, float* __restrict__ tab) {
  int idx = blockIdx.x * 256 + threadIdx.x;
  if (idx >= 324 * 96) return;
  int c = idx % 96, p = idx / 96;
  int Dm, fo, pl;
  if (p < 24)       { Dm = 24; fo = 0;   pl = p; }
  else if (p < 120) { Dm = 96; fo = 64;  pl = p - 24; }
  else if (p < 216) { Dm = 96; fo = 128; pl = p - 120; }
  else if (p < 228) { Dm = 12; fo = 0;   pl = p - 216; }
  else if (p < 276) { Dm = 48; fo = 64;  pl = p - 228; }
  else              { Dm = 48; fo = 128; pl = p - 276; }
  float pos = (float)pl / ((float)(Dm - 1) + 1e-6f) * 6.2831853071795864769f;
  float acc = 0.f;
  for (int i = 0; i < 32; ++i) {
    float inv = powf(10000.f, -(float)i / 32.f);
    float a = pos * inv;
    acc += sinf(a) * pos_w[c * 192 + fo + 2 * i] + cosf(a) * pos_w[c * 192 + fo + 2 * i + 1];
  }
  tab[p * 96 + c] = acc;
}

// ---------------- wavelet: low = s3*sum8, xm = 2sqrt2*x(odd,odd,odd) ----------------
__global__ void k_wav(const float* __restrict__ mem, float* __restrict__ xm_g,
                      float* __restrict__ low_g, float* __restrict__ gsum) {
  __shared__ float sxm[96][49];
  __shared__ float slow[96][49];
  int dk = blockIdx.x / 48, hk = blockIdx.x % 48;
  int tid = threadIdx.x;
  for (int idx = tid; idx < 96 * 48; idx += 256) {
    int wk = idx % 48, c = idx / 48;
    const float* p = mem + (((size_t)c * 24 + 2 * dk) * 96 + 2 * hk) * 96 + 2 * wk;
    float s = p[0] + p[1] + p[96] + p[97];
    const float* p2 = p + 96 * 96;
    float x111 = p2[97];
    s += p2[0] + p2[1] + p2[96] + x111;
    sxm[c][wk] = 2.8284271247461903f * x111;
    slow[c][wk] = 0.35355339059327373f * s;
  }
  __syncthreads();
  int n0 = (dk * 48 + hk) * 48;
  for (int idx = tid; idx < 96 * 48; idx += 256) {
    int c = idx % 96, t = idx / 96;
    xm_g[(size_t)(n0 + t) * 96 + c] = sxm[c][t];
    low_g[(size_t)(n0 + t) * 96 + c] = slow[c][t];
  }
  if (tid < 96) {
    float a = 0.f;
    for (int t = 0; t < 48; ++t) a += sxm[tid][t];
    atomicAdd(&gsum[tid], a);
  }
}

// ---------------- global gate MLP (1 block) ----------------
__global__ void k_glo(const float* __restrict__ gsum, const float* __restrict__ g_w1,
                      const float* __restrict__ g_b1, const float* __restrict__ g_w2,
                      const float* __restrict__ g_b2, float* __restrict__ glo) {
  __shared__ float sg[96], sh[96];
  int t = threadIdx.x;
  if (t < 96) sg[t] = gsum[t] * (1.f / 27648.f);
  __syncthreads();
  if (t < 96) {
    float a = g_b1[t];
    for (int i = 0; i < 96; ++i) a += sg[i] * g_w1[t * 96 + i];
    sh[t] = fmaxf(a, 0.f);
  }
  __syncthreads();
  if (t < 96) {
    float a = g_b2[t];
    for (int i = 0; i < 96; ++i) a += sh[i] * g_w2[t * 96 + i];
    glo[t] = a;
  }
}

// ---------------- local gating MLP + fre ----------------
__global__ __launch_bounds__(512) void k_gate(
    const float* __restrict__ xm_g, const float* __restrict__ low_g,
    const float* __restrict__ l_w1, const float* __restrict__ l_b1,
    const float* __restrict__ l_w2, const float* __restrict__ l_b2,
    const float* __restrict__ glo, float* __restrict__ fre) {
  __shared__ float sxm[64][97];
  __shared__ float sH[64][97];
  __shared__ float sW1[96][97];
  __shared__ float sW2[96][97];
  __shared__ float sb1[96], sb2[96], sglo[96];
  int tid = threadIdx.x;
  int n0 = blockIdx.x * 64;
  for (int idx = tid; idx < 64 * 96; idx += 512) {
    int c = idx % 96, t = idx / 96;
    sxm[t][c] = xm_g[(size_t)(n0 + t) * 96 + c];
  }
  for (int idx = tid; idx < 96 * 96; idx += 512) {
    int ci = idx % 96, co = idx / 96;
    sW1[co][ci] = l_w1[idx];
    sW2[co][ci] = l_w2[idx];
  }
  if (tid < 96) { sb1[tid] = l_b1[tid]; sb2[tid] = l_b2[tid]; sglo[tid] = glo[tid]; }
  __syncthreads();
  for (int idx = tid; idx < 64 * 96; idx += 512) {
    int co = idx % 96, t = idx / 96;
    float a = sb1[co];
    for (int ci = 0; ci < 96; ++ci) a += sxm[t][ci] * sW1[co][ci];
    sH[t][co] = fmaxf(a, 0.f);
  }
  __syncthreads();
  for (int idx = tid; idx < 64 * 96; idx += 512) {
    int co = idx % 96, t = idx / 96;
    float a = sb2[co];
    for (int ci = 0; ci < 96; ++ci) a += sH[t][ci] * sW2[co][ci];
    float wg = 1.f / (1.f + expf(-(a + sglo[co])));
    size_t off = (size_t)(n0 + t) * 96 + co;
    float lo = low_g[off];
    fre[off] = wg * (sxm[t][co] - lo) + lo;
  }
}

// ---------------- k/v projection (k gets +pos) ----------------
__global__ void k_kv(const float* __restrict__ fre, const float* __restrict__ tab,
                     const float* __restrict__ in_w, const float* __restrict__ in_b,
                     float* __restrict__ kp, float* __restrict__ vp) {
  __shared__ float sf[96][49];
  __shared__ float skn[96][49];
  __shared__ float sWk[96][97];
  __shared__ float sWv[96][97];
  int tid = threadIdx.x;
  int dk = blockIdx.x / 48, hk = blockIdx.x % 48;
  int n0 = (dk * 48 + hk) * 48;
  for (int idx = tid; idx < 48 * 96; idx += 256) {
    int c = idx % 96, t = idx / 96;
    sf[c][t] = fre[(size_t)(n0 + t) * 96 + c];
  }
  for (int idx = tid; idx < 96 * 96; idx += 256) {
    int ci = idx % 96, co = idx / 96;
    sWk[co][ci] = in_w[96 * 96 + idx];
    sWv[co][ci] = in_w[2 * 96 * 96 + idx];
  }
  __syncthreads();
  const float* azk = tab + 20736 + dk * 96;
  const float* ayk = tab + 21888 + hk * 96;
  const float* axk = tab + 26496;
  for (int idx = tid; idx < 48 * 96; idx += 256) {
    int c = idx % 96, t = idx / 96;
    skn[c][t] = sf[c][t] + azk[c] + ayk[c] + axk[t * 96 + c];
  }
  __syncthreads();
  for (int idx = tid; idx < 48 * 96; idx += 256) {
    int co = idx % 96, t = idx / 96;
    float ak = in_b[96 + co], av = in_b[192 + co];
    for (int ci = 0; ci < 96; ++ci) {
      ak += sWk[co][ci] * skn[ci][t];
      av += sWv[co][ci] * sf[ci][t];
    }
    kp[(size_t)(n0 + t) * 96 + co] = ak;
    vp[(size_t)(n0 + t) * 96 + co] = av;
  }
}

// ---------------- fused attention: qproj + QK^T + softmax + PV + out-proj + LN ----------------
__global__ __launch_bounds__(512) void k_att(
    const float* __restrict__ query, const float* __restrict__ tab,
    const float* __restrict__ kp, const float* __restrict__ vp,
    const float* __restrict__ in_w, const float* __restrict__ in_b,
    const float* __restrict__ out_w, const float* __restrict__ out_b,
    const float* __restrict__ ln_w, const float* __restrict__ ln_b,
    float* __restrict__ out) {
  __shared__ float smem[35448];
  float* sk  = smem;          // [108][97]
  float* sv  = smem + 10476;  // [108][97]
  float* sqp = smem + 20952;  // [48][97]
  float* ss  = smem + 25608;  // [48][108]; first reused as qin [48][97]
  float* sO  = smem + 30792;  // [48][97]
  int tid = threadIdx.x;
  int nw = blockIdx.x, chunk = blockIdx.y;
  int dg = nw / 64, hg = (nw / 8) % 8, wg = nw % 8;
  int l0 = chunk * 48;

  // load k,v rows of this window
  for (int idx = tid; idx < 108 * 96; idx += 512) {
    int co = idx % 96, row = idx / 96;
    int ld = row / 36, lh = (row / 6) % 6, lw = row % 6;
    int n = ((dg * 3 + ld) * 48 + hg * 6 + lh) * 48 + wg * 6 + lw;
    sk[row * 97 + co] = kp[(size_t)n * 96 + co];
    sv[row * 97 + co] = vp[(size_t)n * 96 + co];
  }
  // load qin = q_tok + pos into ss region
  float* sqin = ss;
  for (int idx = tid; idx < 48 * 96; idx += 512) {
    int r = idx % 48, c = idx / 48;
    int l = l0 + r;
    int ld = l / 144, lh = (l / 12) % 12, lw = l % 12;
    int d = dg * 6 + ld, h = hg * 12 + lh, w = wg * 12 + lw;
    float v = query[(((size_t)c * 24 + d) * 96 + h) * 96 + w];
    v += tab[d * 96 + c] + tab[2304 + h * 96 + c] + tab[11520 + w * 96 + c];
    sqin[r * 97 + c] = v;
  }
  __syncthreads();
  // q projection (Wq from global; broadcast-friendly mapping)
  for (int idx = tid; idx < 48 * 96; idx += 512) {
    int r = idx % 48, co = idx / 48;
    float a = in_b[co];
    const float* wrow = in_w + co * 96;
    for (int ci = 0; ci < 96; ++ci) a += sqin[r * 97 + ci] * wrow[ci];
    sqp[r * 97 + co] = a;
  }
  __syncthreads();
  const float scale = 0.28867513459481287f;  // 1/sqrt(12)
  for (int hh = 0; hh < 8; ++hh) {
    int hb = hh * 12;
    for (int idx = tid; idx < 48 * 108; idx += 512) {
      int r = idx / 108, kk = idx % 108;
      float a = 0.f;
      #pragma unroll
      for (int d = 0; d < 12; ++d) a += sqp[r * 97 + hb + d] * sk[kk * 97 + hb + d];
      ss[r * 108 + kk] = a * scale;
    }
    __syncthreads();
    if (tid < 384) {
      int row = tid / 8, sub = tid % 8;
      float m = -1e30f;
      for (int kk = sub; kk < 108; kk += 8) m = fmaxf(m, ss[row * 108 + kk]);
      for (int o = 1; o < 8; o <<= 1) m = fmaxf(m, __shfl_xor(m, o, 8));
      float sum = 0.f;
      for (int kk = sub; kk < 108; kk += 8) {
        float e = expf(ss[row * 108 + kk] - m);
        ss[row * 108 + kk] = e;
        sum += e;
      }
      for (int o = 1; o < 8; o <<= 1) sum += __shfl_xor(sum, o, 8);
      float inv = 1.f / sum;
      for (int kk = sub; kk < 108; kk += 8) ss[row * 108 + kk] *= inv;
    }
    __syncthreads();
    for (int idx = tid; idx < 48 * 12; idx += 512) {
      int r = idx / 12, d = idx % 12;
      float a = 0.f;
      for (int kk = 0; kk < 108; ++kk) a += ss[r * 108 + kk] * sv[kk * 97 + hb + d];
      sO[r * 97 + hb + d] = a;
    }
    __syncthreads();
  }
  // stage out_w into sk region
  float* sWo = smem;
  for (int idx = tid; idx < 96 * 96; idx += 512) {
    int ci = idx % 96, co = idx / 96;
    sWo[co * 97 + ci] = out_w[idx];
  }
  __syncthreads();
  // out proj + residual(q_tok)
  float* sR = smem + 10476;
  for (int idx = tid; idx < 48 * 96; idx += 512) {
    int r = idx % 48, co = idx / 48;
    float a = out_b[co];
    for (int ci = 0; ci < 96; ++ci) a += sO[r * 97 + ci] * sWo[co * 97 + ci];
    int l = l0 + r;
    int ld = l / 144, lh = (l / 12) % 12, lw = l % 12;
    int d = dg * 6 + ld, h = hg * 12 + lh, w = wg * 12 + lw;
    a += query[(((size_t)co * 24 + d) * 96 + h) * 96 + w];
    sR[r * 97 + co] = a;
  }
  __syncthreads();
  // LayerNorm over channels
  if (tid < 384) {
    int row = tid / 8, sub = tid % 8;
    float s = 0.f, s2 = 0.f;
    for (int co = sub; co < 96; co += 8) {
      float v = sR[row * 97 + co];
      s += v; s2 += v * v;
    }
    for (int o = 1; o < 8; o <<= 1) { s += __shfl_xor(s, o, 8); s2 += __shfl_xor(s2, o, 8); }
    float mu = s * (1.f / 96.f);
    float var = s2 * (1.f / 96.f) - mu * mu;
    float rstd = rsqrtf(var + 1e-5f);
    for (int co = sub; co < 96; co += 8) {
      sR[row * 97 + co] = (sR[row * 97 + co] - mu) * rstd * ln_w[co] + ln_b[co];
    }
  }
  __syncthreads();
  // write output (reverse partition)
  for (int idx = tid; idx < 48 * 96; idx += 512) {
    int r = idx % 48, co = idx / 48;
    int l = l0 + r;
    int ld = l / 144, lh = (l / 12) % 12, lw = l % 12;
    int d = dg * 6 + ld, h = hg * 12 + lh, w = wg * 12 + lw;
    out[(((size_t)co * 24 + d) * 96 + h) * 96 + w] = sR[r * 97 + co];
  }
}

extern "C" void kernel_launch(void* const* d_in, const int* in_sizes, int n_in,
                              void* d_out, int out_size, void* d_ws, size_t ws_size,
                              hipStream_t stream) {
  const float* query = (const float*)d_in[0];
  const float* mem   = (const float*)d_in[1];
  const float* pos_w = (const float*)d_in[2];
  const float* l_w1  = (const float*)d_in[3];
  const float* l_b1  = (const float*)d_in[4];
  const float* l_w2  = (const float*)d_in[5];
  const float* l_b2  = (const float*)d_in[6];
  const float* g_w1  = (const float*)d_in[7];
  const float* g_b1  = (const float*)d_in[8];
  const float* g_w2  = (const float*)d_in[9];
  const float* g_b2  = (const float*)d_in[10];
  const float* in_w  = (const float*)d_in[11];
  const float* in_b  = (const float*)d_in[12];
  const float* out_w = (const float*)d_in[13];
  const float* out_b = (const float*)d_in[14];
  const float* ln_w  = (const float*)d_in[15];
  const float* ln_b  = (const float*)d_in[16];
  float* ws   = (float*)d_ws;
  float* tab  = ws + OFF_TAB;
  float* gsum = ws + OFF_GSUM;
  float* glo  = ws + OFF_GLO;
  float* xm   = ws + OFF_XM;
  float* low  = ws + OFF_LOW;
  float* fre  = ws + OFF_FRE;
  float* kpb  = ws + OFF_KP;
  float* vpb  = ws + OFF_VP;

  hipMemsetAsync(gsum, 0, 96 * sizeof(float), stream);
  k_pos<<<(324 * 96 + 255) / 256, 256, 0, stream>>>(pos_w, tab);
  k_wav<<<576, 256, 0, stream>>>(mem, xm, low, gsum);
  k_glo<<<1, 128, 0, stream>>>(gsum, g_w1, g_b1, g_w2, g_b2, glo);
  k_gate<<<432, 512, 0, stream>>>(xm, low, l_w1, l_b1, l_w2, l_b2, glo, fre);
  k_kv<<<576, 256, 0, stream>>>(fre, tab, in_w, in_b, kpb, vpb);
  k_att<<<dim3(256, 18), 512, 0, stream>>>(query, tab, kpb, vpb, in_w, in_b,
                                           out_w, out_b, ln_w, ln_b, (float*)d_out);
}

// Round 4
// 519.493 us; speedup vs baseline: 4.1168x; 4.1168x over previous
//
#include <hip/hip_runtime.h>
#include <math.h>

// Geometry: C=96, NHEAD=8, dh=12 (pad 16), D,H,W=24,96,96; wavelet grid 12,48,48
// windows 4x8x8=256, Lq=864 (54 m-tiles of 16), Lk=108 (pad 112/128)

using short8 = __attribute__((ext_vector_type(8))) short;
using f32x4  = __attribute__((ext_vector_type(4))) float;

__device__ __forceinline__ unsigned short f2bf(float f) {
  unsigned u = __builtin_bit_cast(unsigned, f);
  unsigned r = u + 0x7fffu + ((u >> 16) & 1u);
  return (unsigned short)(r >> 16);
}
__device__ __forceinline__ float bf2f(unsigned short b) {
  unsigned u = ((unsigned)b) << 16;
  return __builtin_bit_cast(float, u);
}

// workspace byte offsets (high-water ~35.9 MB; round-1 proved >=53.2 MB usable)
#define OFFB_TAB   0u          // 31104 f32
#define OFFB_GSUM  124416u     // 96 f32
#define OFFB_GLO   124800u     // 96 f32
#define OFFB_XM    125184u     // 2654208 f32 (reused in-place as fre)
#define OFFB_LOW   10742016u   // 2654208 f32
#define OFFB_WQ    21358848u   // 9216 bf16
#define OFFB_WK    21377280u
#define OFFB_WV    21395712u
#define OFFB_WO    21414144u
#define OFFB_KP    21432576u   // 27648*128 bf16 = 7077888 B (zero-padded head cols)
#define OFFB_VT    28510464u   // 32768*112 bf16 = 7340032 B (+256 B over-read pad)
#define MEMSET_OFF 21432576u
#define MEMSET_LEN 14418176u   // kp + vt + pad

// ---------------- pos tables: tab[p*96+c], p in [0,324) ----------------
__global__ void k_pos(const float* __restrict__ pos_w, float* __restrict__ tab) {
  int idx = blockIdx.x * 256 + threadIdx.x;
  if (idx >= 324 * 96) return;
  int c = idx % 96, p = idx / 96;
  int Dm, fo, pl;
  if (p < 24)       { Dm = 24; fo = 0;   pl = p; }
  else if (p < 120) { Dm = 96; fo = 64;  pl = p - 24; }
  else if (p < 216) { Dm = 96; fo = 128; pl = p - 120; }
  else if (p < 228) { Dm = 12; fo = 0;   pl = p - 216; }
  else if (p < 276) { Dm = 48; fo = 64;  pl = p - 228; }
  else              { Dm = 48; fo = 128; pl = p - 276; }
  float pos = (float)pl / ((float)(Dm - 1) + 1e-6f) * 6.2831853071795864769f;
  float acc = 0.f;
  for (int i = 0; i < 32; ++i) {
    float inv = powf(10000.f, -(float)i / 32.f);
    float a = pos * inv;
    acc += sinf(a) * pos_w[c * 192 + fo + 2 * i] + cosf(a) * pos_w[c * 192 + fo + 2 * i + 1];
  }
  tab[p * 96 + c] = acc;
}

// ---------------- weight prep: f32 -> bf16 ----------------
__global__ void k_wprep(const float* __restrict__ in_w, const float* __restrict__ out_w,
                        unsigned short* __restrict__ wq, unsigned short* __restrict__ wk,
                        unsigned short* __restrict__ wv, unsigned short* __restrict__ wo) {
  int i = blockIdx.x * 256 + threadIdx.x;
  if (i < 9216) {
    wq[i] = f2bf(in_w[i]);
    wk[i] = f2bf(in_w[9216 + i]);
    wv[i] = f2bf(in_w[18432 + i]);
    wo[i] = f2bf(out_w[i]);
  }
}

// ---------------- wavelet: low = s3*sum8, xm = 2sqrt2*x(odd,odd,odd) ----------------
__global__ void k_wav(const float* __restrict__ mem, float* __restrict__ xm_g,
                      float* __restrict__ low_g, float* __restrict__ gsum) {
  __shared__ float sxm[96][49];
  __shared__ float slow[96][49];
  int dk = blockIdx.x / 48, hk = blockIdx.x % 48;
  int tid = threadIdx.x;
  for (int idx = tid; idx < 96 * 48; idx += 256) {
    int wk = idx % 48, c = idx / 48;
    const float* p = mem + (((size_t)c * 24 + 2 * dk) * 96 + 2 * hk) * 96 + 2 * wk;
    float s = p[0] + p[1] + p[96] + p[97];
    const float* p2 = p + 96 * 96;
    float x111 = p2[97];
    s += p2[0] + p2[1] + p2[96] + x111;
    sxm[c][wk] = 2.8284271247461903f * x111;
    slow[c][wk] = 0.35355339059327373f * s;
  }
  __syncthreads();
  int n0 = (dk * 48 + hk) * 48;
  for (int idx = tid; idx < 96 * 48; idx += 256) {
    int c = idx % 96, t = idx / 96;
    xm_g[(size_t)(n0 + t) * 96 + c] = sxm[c][t];
    low_g[(size_t)(n0 + t) * 96 + c] = slow[c][t];
  }
  if (tid < 96) {
    float a = 0.f;
    for (int t = 0; t < 48; ++t) a += sxm[tid][t];
    atomicAdd(&gsum[tid], a);
  }
}

// ---------------- global gate MLP (1 block) ----------------
__global__ void k_glo(const float* __restrict__ gsum, const float* __restrict__ g_w1,
                      const float* __restrict__ g_b1, const float* __restrict__ g_w2,
                      const float* __restrict__ g_b2, float* __restrict__ glo) {
  __shared__ float sg[96], sh[96];
  int t = threadIdx.x;
  if (t < 96) sg[t] = gsum[t] * (1.f / 27648.f);
  __syncthreads();
  if (t < 96) {
    float a = g_b1[t];
    for (int i = 0; i < 96; ++i) a += sg[i] * g_w1[t * 96 + i];
    sh[t] = fmaxf(a, 0.f);
  }
  __syncthreads();
  if (t < 96) {
    float a = g_b2[t];
    for (int i = 0; i < 96; ++i) a += sh[i] * g_w2[t * 96 + i];
    glo[t] = a;
  }
}

// ---------------- local gating MLP + fre (fre aliases xm_g in-place; no restrict) ----------------
__global__ __launch_bounds__(512) void k_gate(
    const float* xm_g, const float* __restrict__ low_g,
    const float* __restrict__ l_w1, const float* __restrict__ l_b1,
    const float* __restrict__ l_w2, const float* __restrict__ l_b2,
    const float* __restrict__ glo, float* fre) {
  __shared__ float sxm[64][97];
  __shared__ float sH[64][97];
  __shared__ float sW1[96][97];
  __shared__ float sW2[96][97];
  __shared__ float sb1[96], sb2[96], sglo[96];
  int tid = threadIdx.x;
  int n0 = blockIdx.x * 64;
  for (int idx = tid; idx < 64 * 96; idx += 512) {
    int c = idx % 96, t = idx / 96;
    sxm[t][c] = xm_g[(size_t)(n0 + t) * 96 + c];
  }
  for (int idx = tid; idx < 96 * 96; idx += 512) {
    int ci = idx % 96, co = idx / 96;
    sW1[co][ci] = l_w1[idx];
    sW2[co][ci] = l_w2[idx];
  }
  if (tid < 96) { sb1[tid] = l_b1[tid]; sb2[tid] = l_b2[tid]; sglo[tid] = glo[tid]; }
  __syncthreads();
  for (int idx = tid; idx < 64 * 96; idx += 512) {
    int co = idx % 96, t = idx / 96;
    float a = sb1[co];
    for (int ci = 0; ci < 96; ++ci) a += sxm[t][ci] * sW1[co][ci];
    sH[t][co] = fmaxf(a, 0.f);
  }
  __syncthreads();
  for (int idx = tid; idx < 64 * 96; idx += 512) {
    int co = idx % 96, t = idx / 96;
    float a = sb2[co];
    for (int ci = 0; ci < 96; ++ci) a += sH[t][ci] * sW2[co][ci];
    float wg = 1.f / (1.f + expf(-(a + sglo[co])));
    size_t off = (size_t)(n0 + t) * 96 + co;
    float lo = low_g[off];
    fre[off] = wg * (sxm[t][co] - lo) + lo;
  }
}

// ---------------- k/v projection (MFMA) -> kp[nw*108+kk][128], vt[(nw*8+h)*16+d][112] ----------------
__global__ __launch_bounds__(256) void k_kv2(
    const float* __restrict__ fre, const float* __restrict__ tab,
    const unsigned short* __restrict__ wk, const unsigned short* __restrict__ wv,
    const float* __restrict__ in_b,
    unsigned short* __restrict__ kp, unsigned short* __restrict__ vt) {
  __shared__ unsigned short sKin[112 * 104];
  __shared__ unsigned short sVin[112 * 104];
  __shared__ unsigned short sVt[4 * 96 * 18];
  int tid = threadIdx.x, nw = blockIdx.x;
  int dg = nw >> 6, hg = (nw >> 3) & 7, wg = nw & 7;
  for (int idx = tid; idx < 108 * 48; idx += 256) {
    int row = idx % 108, cop = idx / 108;
    int ld = row / 36, lh = (row / 6) % 6, lw = row % 6;
    int dk = dg * 3 + ld, hk = hg * 6 + lh, wk_ = wg * 6 + lw;
    int n = (dk * 48 + hk) * 48 + wk_;
    int co = cop * 2;
    float f0 = fre[(size_t)n * 96 + co], f1 = fre[(size_t)n * 96 + co + 1];
    float p0 = tab[20736 + dk * 96 + co] + tab[21888 + hk * 96 + co] + tab[26496 + wk_ * 96 + co];
    float p1 = tab[20736 + dk * 96 + co + 1] + tab[21888 + hk * 96 + co + 1] + tab[26496 + wk_ * 96 + co + 1];
    *(unsigned*)(&sKin[row * 104 + co]) = (unsigned)f2bf(f0 + p0) | ((unsigned)f2bf(f1 + p1) << 16);
    *(unsigned*)(&sVin[row * 104 + co]) = (unsigned)f2bf(f0) | ((unsigned)f2bf(f1) << 16);
  }
  __syncthreads();
  int wave = tid >> 6, lane = tid & 63, l15 = lane & 15, g = lane >> 4;
  for (int mt = wave; mt < 7; mt += 4) {
    f32x4 DK[6], DV[6];
    #pragma unroll
    for (int nt = 0; nt < 6; ++nt) { DK[nt] = f32x4{0.f,0.f,0.f,0.f}; DV[nt] = f32x4{0.f,0.f,0.f,0.f}; }
    #pragma unroll
    for (int ks = 0; ks < 3; ++ks) {
      short8 ak = *(const short8*)(&sKin[(mt * 16 + l15) * 104 + ks * 32 + g * 8]);
      short8 av = *(const short8*)(&sVin[(mt * 16 + l15) * 104 + ks * 32 + g * 8]);
      #pragma unroll
      for (int nt = 0; nt < 6; ++nt) {
        short8 bk = *(const short8*)(&wk[(nt * 16 + l15) * 96 + ks * 32 + g * 8]);
        short8 bv = *(const short8*)(&wv[(nt * 16 + l15) * 96 + ks * 32 + g * 8]);
        DK[nt] = __builtin_amdgcn_mfma_f32_16x16x32_bf16(ak, bk, DK[nt], 0, 0, 0);
        DV[nt] = __builtin_amdgcn_mfma_f32_16x16x32_bf16(av, bv, DV[nt], 0, 0, 0);
      }
    }
    #pragma unroll
    for (int nt = 0; nt < 6; ++nt) {
      int co = nt * 16 + l15;
      float bk_ = in_b[96 + co], bv_ = in_b[192 + co];
      #pragma unroll
      for (int r = 0; r < 4; ++r) {
        int row = g * 4 + r;
        int kk = mt * 16 + row;
        float vk = DK[nt][r] + bk_;
        float vk2 = __shfl_xor(vk, 1);
        if (!(l15 & 1) && kk < 108) {
          unsigned pk = (unsigned)f2bf(vk) | ((unsigned)f2bf(vk2) << 16);
          *(unsigned*)(&kp[((size_t)nw * 108 + kk) * 128 + (co / 12) * 16 + co % 12]) = pk;
        }
        float vv = DV[nt][r] + bv_;
        sVt[wave * 1728 + co * 18 + row] = f2bf(vv);
      }
    }
    asm volatile("s_waitcnt lgkmcnt(0)" ::: "memory");
    int cnt = (mt == 6) ? 12 : 16;
    for (int co = lane; co < 96; co += 64) {
      int hh = co / 12, dd = co % 12;
      size_t vrow = ((size_t)(nw * 8 + hh) * 16 + dd) * 112 + mt * 16;
      for (int kk2 = 0; kk2 < cnt; kk2 += 2) {
        unsigned v = *(const unsigned*)(&sVt[wave * 1728 + co * 18 + kk2]);
        *(unsigned*)(&vt[vrow + kk2]) = v;
      }
    }
  }
}

// ---------------- fused attention (MFMA): qproj + QK^T + softmax + PV + out-proj + LN ----------------
// LDS 146688 B: sK[112][136] @0, sWq[96][104] @30464, 8 waves @50432 + wave*12032:
//   qtile [16][136] (+0, pads zero), sPq [16][136] (+4352, qin/P/R overlay), sO [16][104] (+8704)
__global__ __launch_bounds__(512) void k_att2(
    const float* __restrict__ query, const float* __restrict__ tab,
    const unsigned short* __restrict__ kp, const unsigned short* __restrict__ vt,
    const unsigned short* __restrict__ wq, const unsigned short* __restrict__ wo,
    const float* __restrict__ in_b, const float* __restrict__ out_b,
    const float* __restrict__ ln_w, const float* __restrict__ ln_b,
    float* __restrict__ out) {
  __shared__ __align__(16) unsigned char smem[146688];
  unsigned short* sK  = (unsigned short*)smem;
  unsigned short* sWq = (unsigned short*)(smem + 30464);
  int tid = threadIdx.x;
  int nw = blockIdx.x;
  int dg = nw >> 6, hg = (nw >> 3) & 7, wg = nw & 7;
  int wave = tid >> 6, lane = tid & 63, l15 = lane & 15, g = lane >> 4;
  unsigned short* qtile = (unsigned short*)(smem + 50432 + wave * 12032);
  unsigned short* sPq   = qtile + 2176;   // [16][136]
  unsigned short* sO    = qtile + 4352;   // [16][104]

  // zero all per-wave regions (pads must be 0; rest harmless)
  for (int c = tid; c < 6016; c += 512)
    *(int4*)(smem + 50432 + c * 16) = int4{0, 0, 0, 0};
  // stage K (head-padded cols already zeroed in kp via memset)
  for (int c = tid; c < 108 * 16; c += 512) {
    int row = c >> 4, ch = c & 15;
    *(int4*)(&sK[row * 136 + ch * 8]) = *(const int4*)(&kp[((size_t)nw * 108 + row) * 128 + ch * 8]);
  }
  // stage Wq
  for (int c = tid; c < 96 * 12; c += 512) {
    int row = c / 12, ch = c % 12;
    *(int4*)(&sWq[row * 104 + ch * 8]) = *(const int4*)(&wq[row * 96 + ch * 8]);
  }
  __syncthreads();

  const float scale = 0.28867513459481287f;  // 1/sqrt(12)
  float biasq[6], biaso[6];
  #pragma unroll
  for (int nt = 0; nt < 6; ++nt) {
    biasq[nt] = in_b[nt * 16 + l15];
    biaso[nt] = out_b[nt * 16 + l15];
  }

  for (int mt = wave; mt < 54; mt += 8) {
    // ---- stage qin = q_tok + pos into sPq cols 0..95 ----
    for (int c = lane; c < 16 * 48; c += 64) {
      int row = c & 15, cop = c >> 4;
      int co = cop * 2;
      int l = mt * 16 + row;
      int ld = l / 144, lh = (l / 12) % 12, lw = l % 12;
      int d = dg * 6 + ld, h = hg * 12 + lh, w = wg * 12 + lw;
      size_t qoff = (((size_t)co * 24 + d) * 96 + h) * 96 + w;
      float v0 = query[qoff] + tab[d * 96 + co] + tab[2304 + h * 96 + co] + tab[11520 + w * 96 + co];
      float v1 = query[qoff + 221184] + tab[d * 96 + co + 1] + tab[2304 + h * 96 + co + 1] + tab[11520 + w * 96 + co + 1];
      *(unsigned*)(&sPq[row * 136 + co]) = (unsigned)f2bf(v0) | ((unsigned)f2bf(v1) << 16);
    }
    // ---- q projection: qtile[16][head-padded 128] = qin @ Wq^T + bq ----
    {
      f32x4 QD[6];
      #pragma unroll
      for (int nt = 0; nt < 6; ++nt) QD[nt] = f32x4{0.f, 0.f, 0.f, 0.f};
      #pragma unroll
      for (int ks = 0; ks < 3; ++ks) {
        short8 a = *(const short8*)(&sPq[l15 * 136 + ks * 32 + g * 8]);
        #pragma unroll
        for (int nt = 0; nt < 6; ++nt) {
          short8 bw = *(const short8*)(&sWq[(nt * 16 + l15) * 104 + ks * 32 + g * 8]);
          QD[nt] = __builtin_amdgcn_mfma_f32_16x16x32_bf16(a, bw, QD[nt], 0, 0, 0);
        }
      }
      #pragma unroll
      for (int nt = 0; nt < 6; ++nt) {
        int co = nt * 16 + l15;
        #pragma unroll
        for (int r = 0; r < 4; ++r) {
          float v = QD[nt][r] + biasq[nt];
          float v2 = __shfl_xor(v, 1);
          if (!(l15 & 1)) {
            int row = g * 4 + r;
            int hh = co / 12, dd = co % 12;
            unsigned pk = (unsigned)f2bf(v) | ((unsigned)f2bf(v2) << 16);
            *(unsigned*)(&qtile[row * 136 + hh * 16 + dd]) = pk;
          }
        }
      }
    }
    // ---- per-head: QK^T + softmax + PV ----
    #pragma unroll 1
    for (int h = 0; h < 8; ++h) {
      short8 aq = short8{0,0,0,0,0,0,0,0};
      if (lane < 32) aq = *(const short8*)(&qtile[l15 * 136 + h * 16 + g * 8]);
      f32x4 S[7];
      #pragma unroll
      for (int nt = 0; nt < 7; ++nt) {
        short8 bk = short8{0,0,0,0,0,0,0,0};
        if (lane < 32) bk = *(const short8*)(&sK[(nt * 16 + l15) * 136 + h * 16 + g * 8]);
        S[nt] = __builtin_amdgcn_mfma_f32_16x16x32_bf16(aq, bk, f32x4{0.f,0.f,0.f,0.f}, 0, 0, 0);
      }
      float mx0 = -3e38f, mx1 = -3e38f, mx2 = -3e38f, mx3 = -3e38f;
      #pragma unroll
      for (int nt = 0; nt < 7; ++nt) {
        bool valid = (nt < 6) || (l15 < 12);
        #pragma unroll
        for (int r = 0; r < 4; ++r) {
          float s = S[nt][r] * scale;
          S[nt][r] = s;
          if (valid) {
            if (r == 0) mx0 = fmaxf(mx0, s);
            else if (r == 1) mx1 = fmaxf(mx1, s);
            else if (r == 2) mx2 = fmaxf(mx2, s);
            else mx3 = fmaxf(mx3, s);
          }
        }
      }
      #pragma unroll
      for (int o = 1; o < 16; o <<= 1) {
        mx0 = fmaxf(mx0, __shfl_xor(mx0, o, 16));
        mx1 = fmaxf(mx1, __shfl_xor(mx1, o, 16));
        mx2 = fmaxf(mx2, __shfl_xor(mx2, o, 16));
        mx3 = fmaxf(mx3, __shfl_xor(mx3, o, 16));
      }
      float sm0 = 0.f, sm1 = 0.f, sm2 = 0.f, sm3 = 0.f;
      #pragma unroll
      for (int nt = 0; nt < 7; ++nt) {
        bool valid = (nt < 6) || (l15 < 12);
        #pragma unroll
        for (int r = 0; r < 4; ++r) {
          float m = (r == 0) ? mx0 : (r == 1) ? mx1 : (r == 2) ? mx2 : mx3;
          float e = valid ? __expf(S[nt][r] - m) : 0.f;
          S[nt][r] = e;
          if (r == 0) sm0 += e; else if (r == 1) sm1 += e; else if (r == 2) sm2 += e; else sm3 += e;
        }
      }
      #pragma unroll
      for (int o = 1; o < 16; o <<= 1) {
        sm0 += __shfl_xor(sm0, o, 16);
        sm1 += __shfl_xor(sm1, o, 16);
        sm2 += __shfl_xor(sm2, o, 16);
        sm3 += __shfl_xor(sm3, o, 16);
      }
      float iv0 = 1.f / sm0, iv1 = 1.f / sm1, iv2 = 1.f / sm2, iv3 = 1.f / sm3;
      #pragma unroll
      for (int nt = 0; nt < 7; ++nt) {
        #pragma unroll
        for (int r = 0; r < 4; ++r) {
          float iv = (r == 0) ? iv0 : (r == 1) ? iv1 : (r == 2) ? iv2 : iv3;
          float p = S[nt][r] * iv;
          float p2 = __shfl_xor(p, 1);
          if (!(l15 & 1)) {
            unsigned pk = (unsigned)f2bf(p) | ((unsigned)f2bf(p2) << 16);
            *(unsigned*)(&sPq[(g * 4 + r) * 136 + nt * 16 + l15]) = pk;
          }
        }
      }
      asm volatile("s_waitcnt lgkmcnt(0)" ::: "memory");
      // PV: A = P from LDS, B = V^T fragments straight from global (L1-resident)
      f32x4 acc = f32x4{0.f, 0.f, 0.f, 0.f};
      const unsigned short* vrow = vt + ((size_t)(nw * 128) + h * 16 + l15) * 112;
      #pragma unroll
      for (int ks = 0; ks < 4; ++ks) {
        short8 pa = *(const short8*)(&sPq[l15 * 136 + ks * 32 + g * 8]);
        short8 vb = *(const short8*)(&vrow[ks * 32 + g * 8]);
        acc = __builtin_amdgcn_mfma_f32_16x16x32_bf16(pa, vb, acc, 0, 0, 0);
      }
      #pragma unroll
      for (int r = 0; r < 4; ++r) {
        float v = acc[r];
        float v2 = __shfl_xor(v, 1);
        if (!(l15 & 1) && l15 < 12) {
          unsigned pk = (unsigned)f2bf(v) | ((unsigned)f2bf(v2) << 16);
          *(unsigned*)(&sO[(g * 4 + r) * 104 + h * 12 + l15]) = pk;
        }
      }
    } // heads
    asm volatile("s_waitcnt lgkmcnt(0)" ::: "memory");
    // ---- out-proj: R[16][96] = O[16][96] @ Wo^T ----
    f32x4 R[6];
    #pragma unroll
    for (int nt = 0; nt < 6; ++nt) R[nt] = f32x4{0.f, 0.f, 0.f, 0.f};
    #pragma unroll
    for (int ks = 0; ks < 3; ++ks) {
      short8 a = *(const short8*)(&sO[l15 * 104 + ks * 32 + g * 8]);
      #pragma unroll
      for (int nt = 0; nt < 6; ++nt) {
        short8 b = *(const short8*)(&wo[(nt * 16 + l15) * 96 + ks * 32 + g * 8]);
        R[nt] = __builtin_amdgcn_mfma_f32_16x16x32_bf16(a, b, R[nt], 0, 0, 0);
      }
    }
    #pragma unroll
    for (int nt = 0; nt < 6; ++nt) {
      int co = nt * 16 + l15;
      #pragma unroll
      for (int r = 0; r < 4; ++r) {
        float v = R[nt][r] + biaso[nt];
        float v2 = __shfl_xor(v, 1);
        if (!(l15 & 1)) {
          unsigned pk = (unsigned)f2bf(v) | ((unsigned)f2bf(v2) << 16);
          *(unsigned*)(&sPq[(g * 4 + r) * 136 + co]) = pk;
        }
      }
    }
    asm volatile("s_waitcnt lgkmcnt(0)" ::: "memory");
    // ---- residual + LN + store (row = l15; g covers co = g + 4i) ----
    {
      int l = mt * 16 + l15;
      int ld = l / 144, lh = (l / 12) % 12, lw = l % 12;
      int d = dg * 6 + ld, h_ = hg * 12 + lh, w_ = wg * 12 + lw;
      size_t sp = ((size_t)d * 96 + h_) * 96 + w_;
      float vals[24];
      float s = 0.f, s2 = 0.f;
      #pragma unroll
      for (int i = 0; i < 24; ++i) {
        int co = g + 4 * i;
        float v = bf2f(sPq[l15 * 136 + co]) + query[(size_t)co * 221184 + sp];
        vals[i] = v;
        s += v; s2 += v * v;
      }
      s += __shfl_xor(s, 16); s2 += __shfl_xor(s2, 16);
      s += __shfl_xor(s, 32); s2 += __shfl_xor(s2, 32);
      float mu = s * (1.f / 96.f);
      float var = s2 * (1.f / 96.f) - mu * mu;
      float rstd = rsqrtf(var + 1e-5f);
      #pragma unroll
      for (int i = 0; i < 24; ++i) {
        int co = g + 4 * i;
        out[(size_t)co * 221184 + sp] = (vals[i] - mu) * rstd * ln_w[co] + ln_b[co];
      }
    }
  } // m-tiles
}

extern "C" void kernel_launch(void* const* d_in, const int* in_sizes, int n_in,
                              void* d_out, int out_size, void* d_ws, size_t ws_size,
                              hipStream_t stream) {
  const float* query = (const float*)d_in[0];
  const float* mem   = (const float*)d_in[1];
  const float* pos_w = (const float*)d_in[2];
  const float* l_w1  = (const float*)d_in[3];
  const float* l_b1  = (const float*)d_in[4];
  const float* l_w2  = (const float*)d_in[5];
  const float* l_b2  = (const float*)d_in[6];
  const float* g_w1  = (const float*)d_in[7];
  const float* g_b1  = (const float*)d_in[8];
  const float* g_w2  = (const float*)d_in[9];
  const float* g_b2  = (const float*)d_in[10];
  const float* in_w  = (const float*)d_in[11];
  const float* in_b  = (const float*)d_in[12];
  const float* out_w = (const float*)d_in[13];
  const float* out_b = (const float*)d_in[14];
  const float* ln_w  = (const float*)d_in[15];
  const float* ln_b  = (const float*)d_in[16];
  unsigned char* ws = (unsigned char*)d_ws;
  float* tab  = (float*)(ws + OFFB_TAB);
  float* gsum = (float*)(ws + OFFB_GSUM);
  float* glo  = (float*)(ws + OFFB_GLO);
  float* xm   = (float*)(ws + OFFB_XM);   // reused in-place as fre
  float* low  = (float*)(ws + OFFB_LOW);
  unsigned short* wq = (unsigned short*)(ws + OFFB_WQ);
  unsigned short* wk = (unsigned short*)(ws + OFFB_WK);
  unsigned short* wv = (unsigned short*)(ws + OFFB_WV);
  unsigned short* wo = (unsigned short*)(ws + OFFB_WO);
  unsigned short* kp = (unsigned short*)(ws + OFFB_KP);
  unsigned short* vt = (unsigned short*)(ws + OFFB_VT);

  hipMemsetAsync(gsum, 0, 96 * sizeof(float), stream);
  hipMemsetAsync(ws + MEMSET_OFF, 0, MEMSET_LEN, stream);
  k_pos<<<(324 * 96 + 255) / 256, 256, 0, stream>>>(pos_w, tab);
  k_wprep<<<36, 256, 0, stream>>>(in_w, out_w, wq, wk, wv, wo);
  k_wav<<<576, 256, 0, stream>>>(mem, xm, low, gsum);
  k_glo<<<1, 128, 0, stream>>>(gsum, g_w1, g_b1, g_w2, g_b2, glo);
  k_gate<<<432, 512, 0, stream>>>(xm, low, l_w1, l_b1, l_w2, l_b2, glo, xm);
  k_kv2<<<256, 256, 0, stream>>>(xm, tab, wk, wv, in_b, kp, vt);
  k_att2<<<256, 512, 0, stream>>>(query, tab, kp, vt, wq, wo, in_b, out_b,
                                  ln_w, ln_b, (float*)d_out);
}